// Round 14
// baseline (104.213 us; speedup 1.0000x reference)
//
#include <hip/hip_runtime.h>

#define B_ 4
#define C_ 4
#define V_ 262144
#define F_ 64
#define K_ 100
#define THETA 0.9f
#define TAU_ 0.1f

typedef unsigned long long ull;

// ---------------- workspace layout (bytes) ----------------
// cs2    : 0       .. 8192     (8 replicas x C x F f32; only c=1..3 used)
// cnt    : 8192    .. 8208     (C f32; only 1..3 used)
// ctrl1  : 8208    .. 8240     (B*2 u32: T1, n_above)
// cntp   : 147456  .. 163840   (1024*4 u32 count partials)  [prep->class_sum]
// cntblk : 147456  .. 151552   (B*256 u32 slot counts)      [collect->select, REUSES cntp]
// hist1p : 163840  .. 688128   (1024*256 u16 hist partials) [prep->class_sum]
// sbits  : 163840  .. 425984   (B*256*64 u32 slot bits)     [collect->select, REUSES hist1p]
// sidx   : 425984  .. 688128   (B*256*64 u32 slot idx)      [collect->select, REUSES hist1p]
// mask16 : 688128  .. 1212416  (B*V/4 u16 packed class masks; bits 1..3)
// wbits  : 1212416 .. 5406720  (B*V u32 product-weight float bits)
// Region reuse is safe: hist1p/cntp are fully rewritten by k_prep and consumed
// by k_class_sum's head blocks BEFORE k_collect overwrites them (serial stream).

// Fused: init + y->mask16/count-partials + proba->wbits/hist1-partials.
__global__ __launch_bounds__(256) void k_prep(const int* __restrict__ y,
                                              const float* __restrict__ proba,
                                              unsigned short* __restrict__ mask16,
                                              unsigned* __restrict__ cntp,
                                              unsigned short* __restrict__ hist1p,
                                              unsigned* __restrict__ wbits,
                                              float* __restrict__ cs2) {
    __shared__ unsigned lh[256];
    __shared__ unsigned wc[4][2];
    int blk = blockIdx.x;
    int tid = threadIdx.x;
    int wave = tid >> 6, lane = tid & 63;
    int b = blk >> 8;
    int i4 = ((blk & 255) << 8) | tid;   // float4-group in [0, V/4)

    lh[tid] = 0u;
    if (blk < 8) cs2[(blk << 8) | tid] = 0.f;   // folded init (consumed later)
    __syncthreads();

    // ---- y (classes 1..3 only; class 0 dead in output) -> masks + counts ----
    const int4* y1 = (const int4*)(y + ((size_t)(b * C_ + 1)) * V_);
    const int4* y2 = (const int4*)(y + ((size_t)(b * C_ + 2)) * V_);
    const int4* y3 = (const int4*)(y + ((size_t)(b * C_ + 3)) * V_);
    int4 yb = y1[i4], yc = y2[i4], yd = y3[i4];

    unsigned n0 = ((unsigned)(yb.x > 0) << 1) | ((unsigned)(yc.x > 0) << 2) | ((unsigned)(yd.x > 0) << 3);
    unsigned n1 = ((unsigned)(yb.y > 0) << 1) | ((unsigned)(yc.y > 0) << 2) | ((unsigned)(yd.y > 0) << 3);
    unsigned n2 = ((unsigned)(yb.z > 0) << 1) | ((unsigned)(yc.z > 0) << 2) | ((unsigned)(yd.z > 0) << 3);
    unsigned n3 = ((unsigned)(yb.w > 0) << 1) | ((unsigned)(yc.w > 0) << 2) | ((unsigned)(yd.w > 0) << 3);
    mask16[(size_t)b * (V_ / 4) + i4] = (unsigned short)(n0 | (n1 << 4) | (n2 << 8) | (n3 << 12));

    unsigned p12 = ((unsigned)(yb.x > 0) + (yb.y > 0) + (yb.z > 0) + (yb.w > 0))
                 | (((unsigned)(yc.x > 0) + (yc.y > 0) + (yc.z > 0) + (yc.w > 0)) << 16);
    unsigned p3 = (unsigned)(yd.x > 0) + (yd.y > 0) + (yd.z > 0) + (yd.w > 0);
    #pragma unroll
    for (int o = 1; o < 64; o <<= 1) {
        p12 += __shfl_xor(p12, o, 64);
        p3 += __shfl_xor(p3, o, 64);
    }
    if (lane == 0) { wc[wave][0] = p12; wc[wave][1] = p3; }

    // ---- proba -> wbits + LDS hist1 ----
    const float* p0 = proba + (size_t)(b * C_) * V_;
    float4 qa = ((const float4*)p0)[i4];
    float4 qb = ((const float4*)(p0 + V_))[i4];
    float4 qc = ((const float4*)(p0 + 2 * V_))[i4];
    float4 qd = ((const float4*)(p0 + 3 * V_))[i4];
    uint4 wb;
    wb.x = __float_as_uint(((qa.x * qb.x) * qc.x) * qd.x);
    wb.y = __float_as_uint(((qa.y * qb.y) * qc.y) * qd.y);
    wb.z = __float_as_uint(((qa.z * qb.z) * qc.z) * qd.z);
    wb.w = __float_as_uint(((qa.w * qb.w) * qc.w) * qd.w);
    ((uint4*)wbits)[(size_t)b * (V_ / 4) + i4] = wb;
    atomicAdd(&lh[wb.x >> 24], 1u);
    atomicAdd(&lh[wb.y >> 24], 1u);
    atomicAdd(&lh[wb.z >> 24], 1u);
    atomicAdd(&lh[wb.w >> 24], 1u);
    __syncthreads();

    hist1p[(blk << 8) | tid] = (unsigned short)lh[tid];
    if (tid == 0) {
        unsigned q12 = wc[0][0] + wc[1][0] + wc[2][0] + wc[3][0];
        unsigned q3 = wc[0][1] + wc[1][1] + wc[2][1] + wc[3][1];
        unsigned* o4 = cntp + (blk << 2);
        o4[0] = 0u; o4[1] = q12 & 0xFFFFu;
        o4[2] = q12 >> 16; o4[3] = q3;
    }
}

// class_sum (c=1..3): blocks 0..3 thresh0, block 4 cnt-reduce (FIRST, so they
// run concurrently with the stream instead of serializing after it);
// blocks 5..1028 stream emb.
__global__ __launch_bounds__(256) void k_class_sum(const float* __restrict__ emb,
                                                   const unsigned short* __restrict__ mask16,
                                                   float* __restrict__ cs2,
                                                   const unsigned short* __restrict__ hist1p,
                                                   const unsigned* __restrict__ cntp,
                                                   unsigned* __restrict__ ctrl1,
                                                   float* __restrict__ cnt) {
    __shared__ unsigned short smask[16384];
    __shared__ unsigned bins[256];
    __shared__ float wsum[4][4];
    int blk = blockIdx.x;
    int tid = threadIdx.x;
    int wave = tid >> 6, lane = tid & 63;

    if (blk < 5) {
        if (blk < 4) {
            int b = blk;
            unsigned s = 0;
            #pragma unroll 8
            for (int c = 0; c < 256; ++c)
                s += hist1p[(((b << 8) | c) << 8) | tid];
            bins[tid] = s;
            __syncthreads();
            if (wave == 0) {
                int binbase = 255 - 4 * lane;
                unsigned c0 = bins[binbase], c1 = bins[binbase - 1], c2 = bins[binbase - 2], c3 = bins[binbase - 3];
                unsigned cnt4 = c0 + c1 + c2 + c3;
                unsigned pref = cnt4;
                #pragma unroll
                for (int o = 1; o < 64; o <<= 1) {
                    unsigned u = __shfl_up(pref, o, 64);
                    if (lane >= o) pref += u;
                }
                unsigned above = pref - cnt4;
                unsigned t = above;
                int found = -1; unsigned nab = 0;
                if (t + c0 >= K_)                { found = binbase;     nab = t; }
                else if (t + c0 + c1 >= K_)      { found = binbase - 1; nab = t + c0; }
                else if (t + c0 + c1 + c2 >= K_) { found = binbase - 2; nab = t + c0 + c1; }
                else if (t + cnt4 >= K_)         { found = binbase - 3; nab = t + c0 + c1 + c2; }
                if (found >= 0 && above < K_) {
                    ctrl1[b * 2] = (unsigned)found;
                    ctrl1[b * 2 + 1] = nab;
                }
            }
        } else if (wave == 0) {
            unsigned s1 = 0, s2 = 0, s3 = 0;
            #pragma unroll
            for (int r = 0; r < 16; ++r) {
                uint4 p = ((const uint4*)cntp)[(r << 6) | lane];
                s1 += p.y; s2 += p.z; s3 += p.w;
            }
            #pragma unroll
            for (int o = 1; o < 64; o <<= 1) {
                s1 += __shfl_xor(s1, o, 64);
                s2 += __shfl_xor(s2, o, 64);
                s3 += __shfl_xor(s3, o, 64);
            }
            if (lane == 0) {
                cnt[0] = 0.f; cnt[1] = (float)s1;
                cnt[2] = (float)s2; cnt[3] = (float)s3;
            }
        }
        return;
    }

    int sblk = blk - 5;
    int s = sblk & 3;
    int f = (sblk >> 2) & 63;
    int b = sblk >> 8;

    {
        const uint4* msrc = (const uint4*)(mask16 + (size_t)b * (V_ / 4) + (s << 14));
        uint4* mdst = (uint4*)smask;
        #pragma unroll
        for (int i = 0; i < 8; ++i) mdst[(i << 8) | tid] = msrc[(i << 8) | tid];
    }
    __syncthreads();

    const float4* ep = (const float4*)emb + ((size_t)((b << 6) | f)) * (V_ / 4) + ((size_t)s << 14);

    float a1 = 0.f, a2 = 0.f, a3 = 0.f;
    for (int o = 0; o < 8; ++o) {
        float4 e[8];
        unsigned mm[8];
        #pragma unroll
        for (int i = 0; i < 8; ++i) e[i] = ep[(((o << 3) | i) << 8) | tid];
        #pragma unroll
        for (int i = 0; i < 8; ++i) mm[i] = smask[(((o << 3) | i) << 8) | tid];
        #pragma unroll
        for (int i = 0; i < 8; ++i) {
            unsigned m = mm[i];
            float4 ev = e[i];
            a1 += ((m >>  1) & 1u ? ev.x : 0.f) + ((m >>  5) & 1u ? ev.y : 0.f)
                + ((m >>  9) & 1u ? ev.z : 0.f) + ((m >> 13) & 1u ? ev.w : 0.f);
            a2 += ((m >>  2) & 1u ? ev.x : 0.f) + ((m >>  6) & 1u ? ev.y : 0.f)
                + ((m >> 10) & 1u ? ev.z : 0.f) + ((m >> 14) & 1u ? ev.w : 0.f);
            a3 += ((m >>  3) & 1u ? ev.x : 0.f) + ((m >>  7) & 1u ? ev.y : 0.f)
                + ((m >> 11) & 1u ? ev.z : 0.f) + ((m >> 15) & 1u ? ev.w : 0.f);
        }
    }
    #pragma unroll
    for (int o = 1; o < 64; o <<= 1) {
        a1 += __shfl_xor(a1, o, 64);
        a2 += __shfl_xor(a2, o, 64);
        a3 += __shfl_xor(a3, o, 64);
    }
    if (lane == 0) { wsum[wave][0] = a1; wsum[wave][1] = a2; wsum[wave][2] = a3; }
    __syncthreads();
    if (tid < 3) {
        float v = wsum[0][tid] + wsum[1][tid] + wsum[2][tid] + wsum[3][tid];
        atomicAdd(&cs2[((sblk & 7) << 8) | ((tid + 1) << 6) | f], v);
    }
}

// T1-level collect into per-block fixed slots (NO global atomics).
__global__ __launch_bounds__(256) void k_collect(const unsigned* __restrict__ wbits,
                                                 const unsigned* __restrict__ ctrl1,
                                                 unsigned* __restrict__ cntblk,
                                                 unsigned* __restrict__ sbits,
                                                 unsigned* __restrict__ sidx) {
    __shared__ unsigned lcnt;
    int blk = blockIdx.x;
    int b = blk >> 8;
    int cb = blk & 255;
    int tid = threadIdx.x;
    if (tid == 0) lcnt = 0u;
    __syncthreads();
    unsigned T1 = ctrl1[b * 2];
    int base = cb << 10;
    int sb = ((b << 8) | cb) << 6;
    #pragma unroll
    for (int it = 0; it < 4; ++it) {
        int v = base + tid + (it << 8);
        unsigned bits = wbits[(size_t)b * V_ + v];
        if ((bits >> 24) >= T1) {
            unsigned pos = atomicAdd(&lcnt, 1u);   // LDS atomic, shallow
            if (pos < 64u) { sbits[sb | pos] = bits; sidx[sb | pos] = (unsigned)v; }
        }
    }
    __syncthreads();
    if (tid == 0) cntblk[(b << 8) | cb] = (lcnt < 64u) ? lcnt : 64u;
}

// bitonic compare-exchange (descending, 512 virtual lanes, 8 keys/lane)
#define XSTEP(kk_, k_, j_) { \
    _Pragma("unroll") \
    for (int r = 0; r < 8; ++r) { \
        ull o = __shfl_xor(kk_[r], (j_) >> 3, 64); \
        int p = (lane << 3) | r; \
        bool keepmax = (((p & (k_)) == 0) == ((p & (j_)) == 0)); \
        kk_[r] = (keepmax == (kk_[r] > o)) ? kk_[r] : o; \
    } }
#define LSTEP(kk_, k_, j_) { \
    _Pragma("unroll") \
    for (int r = 0; r < 8; ++r) { \
        if (!(r & (j_))) { \
            int p = (lane << 3) | r; \
            bool up = ((p & (k_)) == 0); \
            ull a = kk_[r], c = kk_[r | (j_)]; \
            ull mx = a > c ? a : c, mn = a > c ? c : a; \
            kk_[r] = up ? mx : mn; \
            kk_[r | (j_)] = up ? mn : mx; \
        } \
    } }

// Fused refine+select+FINAL: per batch, LDS hist2 -> P16 -> filter -> bitonic,
// then all 4 waves compute the 100 outputs (25 each, 5-deep batched gathers).
__global__ __launch_bounds__(256) void k_select(const unsigned* __restrict__ ctrl1,
                                                const unsigned* __restrict__ cntblk,
                                                const unsigned* __restrict__ sbits,
                                                const unsigned* __restrict__ sidx,
                                                const float* __restrict__ emb,
                                                const int* __restrict__ y,
                                                const float* __restrict__ avg,
                                                const float* __restrict__ cs2,
                                                const float* __restrict__ cnt,
                                                float* __restrict__ out) {
    __shared__ unsigned hist[256];
    __shared__ ull keys[512];
    __shared__ unsigned topv[112];
    __shared__ unsigned P16s, fcnt;
    int b = blockIdx.x;
    int tid = threadIdx.x;
    int wave = tid >> 6, lane = tid & 63;
    unsigned T1 = ctrl1[b * 2];
    unsigned nab = ctrl1[b * 2 + 1];

    hist[tid] = 0u;
    keys[tid] = 0ull;
    keys[tid + 256] = 0ull;
    if (tid == 0) fcnt = 0u;
    __syncthreads();

    int c = (int)cntblk[(b << 8) | tid];   // thread t owns source chunk t
    int sb = ((b << 8) | tid) << 6;
    for (int i = 0; i < c; ++i) {
        unsigned bits = sbits[sb | i];
        if ((bits >> 24) == T1) atomicAdd(&hist[(bits >> 16) & 0xFF], 1u);
    }
    __syncthreads();

    if (wave == 0) {   // descending scan -> T2 -> P16
        int binbase = 255 - 4 * lane;
        unsigned c0 = hist[binbase], c1 = hist[binbase - 1], c2 = hist[binbase - 2], c3 = hist[binbase - 3];
        unsigned cnt4 = c0 + c1 + c2 + c3;
        unsigned pref = cnt4;
        #pragma unroll
        for (int o = 1; o < 64; o <<= 1) {
            unsigned u = __shfl_up(pref, o, 64);
            if (lane >= o) pref += u;
        }
        unsigned above = nab + pref - cnt4;
        unsigned t = above;
        int found = -1;
        if (t + c0 >= K_)                { found = binbase;     }
        else if (t + c0 + c1 >= K_)      { found = binbase - 1; }
        else if (t + c0 + c1 + c2 >= K_) { found = binbase - 2; }
        else if (t + cnt4 >= K_)         { found = binbase - 3; }
        if (found >= 0 && above < K_) P16s = (T1 << 8) | (unsigned)found;
    }
    __syncthreads();

    unsigned P16 = P16s;
    for (int i = 0; i < c; ++i) {
        unsigned bits = sbits[sb | i];
        if ((bits >> 16) >= P16) {
            unsigned pos = atomicAdd(&fcnt, 1u);
            if (pos < 512u) keys[pos] = ((ull)bits << 32) | (unsigned)(~sidx[sb | i]);
        }
    }
    __syncthreads();

    if (wave == 0) {   // exact (bits desc, idx asc) == lax.top_k order
        ull kk[8];
        #pragma unroll
        for (int r = 0; r < 8; ++r) kk[r] = keys[(lane << 3) | r];
        LSTEP(kk, 2, 1)
        LSTEP(kk, 4, 2) LSTEP(kk, 4, 1)
        LSTEP(kk, 8, 4) LSTEP(kk, 8, 2) LSTEP(kk, 8, 1)
        XSTEP(kk, 16, 8) LSTEP(kk, 16, 4) LSTEP(kk, 16, 2) LSTEP(kk, 16, 1)
        XSTEP(kk, 32, 16) XSTEP(kk, 32, 8) LSTEP(kk, 32, 4) LSTEP(kk, 32, 2) LSTEP(kk, 32, 1)
        XSTEP(kk, 64, 32) XSTEP(kk, 64, 16) XSTEP(kk, 64, 8) LSTEP(kk, 64, 4) LSTEP(kk, 64, 2) LSTEP(kk, 64, 1)
        XSTEP(kk, 128, 64) XSTEP(kk, 128, 32) XSTEP(kk, 128, 16) XSTEP(kk, 128, 8) LSTEP(kk, 128, 4) LSTEP(kk, 128, 2) LSTEP(kk, 128, 1)
        XSTEP(kk, 256, 128) XSTEP(kk, 256, 64) XSTEP(kk, 256, 32) XSTEP(kk, 256, 16) XSTEP(kk, 256, 8) LSTEP(kk, 256, 4) LSTEP(kk, 256, 2) LSTEP(kk, 256, 1)
        XSTEP(kk, 512, 256) XSTEP(kk, 512, 128) XSTEP(kk, 512, 64) XSTEP(kk, 512, 32) XSTEP(kk, 512, 16) XSTEP(kk, 512, 8) LSTEP(kk, 512, 4) LSTEP(kk, 512, 2) LSTEP(kk, 512, 1)
        #pragma unroll
        for (int r = 0; r < 8; ++r) {
            int p = (lane << 3) | r;
            if (p < K_) topv[p] = ~(unsigned)(kk[r] & 0xFFFFFFFFull);
        }
    }
    __syncthreads();

    // ---- fused FINAL: nar hoisted per block; wave w does k = 25w..25w+24 ----
    float nar[3];
    #pragma unroll
    for (int cc_ = 1; cc_ < 4; ++cc_) {
        float ccv = cnt[cc_];
        float csum = 0.f;
        #pragma unroll
        for (int rep = 0; rep < 8; ++rep) csum += cs2[(rep << 8) | (cc_ << 6) | lane];
        float mean = csum / fmaxf(ccv, 1.f);
        float av = avg[cc_ * F_ + lane];
        nar[cc_ - 1] = (ccv > 0.f) ? (av * (1.f - THETA) + mean * THETA) : av;
    }
    const float* erow = emb + ((size_t)((b << 6) | lane)) * V_;
    const int* y0p = y + ((size_t)(b * C_ + 0)) * V_;
    const int* y1p = y + ((size_t)(b * C_ + 1)) * V_;
    const int* y2p = y + ((size_t)(b * C_ + 2)) * V_;
    const int* y3p = y + ((size_t)(b * C_ + 3)) * V_;

    for (int j = 0; j < 5; ++j) {
        float ee[5];
        int yv0[5], yv1[5], yv2[5], yv3[5];
        #pragma unroll
        for (int i = 0; i < 5; ++i) {
            unsigned v = topv[wave * 25 + j * 5 + i];
            ee[i] = erow[v];
            yv0[i] = y0p[v]; yv1[i] = y1p[v]; yv2[i] = y2p[v]; yv3[i] = y3p[v];
        }
        #pragma unroll
        for (int i = 0; i < 5; ++i) {
            int k = wave * 25 + j * 5 + i;
            int cm = (yv0[i] > 0) ? 0 : ((yv1[i] > 0) ? 1 : ((yv2[i] > 0) ? 2 : ((yv3[i] > 0) ? 3 : 0)));
            float sel = (cm == 0) ? 1.f : 0.f;
            float t = ee[i] / TAU_;
            float ssum = 0.f;
            #pragma unroll
            for (int cc_ = 0; cc_ < 3; ++cc_) ssum += expf(t * nar[cc_]);
            float term = -logf(ssum);
            #pragma unroll
            for (int o = 32; o > 0; o >>= 1) term += __shfl_down(term, o, 64);
            if (lane == 0) out[b * K_ + k] = term * sel;
        }
    }
}

extern "C" void kernel_launch(void* const* d_in, const int* in_sizes, int n_in,
                              void* d_out, int out_size, void* d_ws, size_t ws_size,
                              hipStream_t stream) {
    const float* proba = (const float*)d_in[0];
    const int* y = (const int*)d_in[1];
    const float* emb = (const float*)d_in[2];
    const float* avg = (const float*)d_in[3];
    float* out = (float*)d_out;

    char* ws = (char*)d_ws;
    float* cs2 = (float*)(ws + 0);
    float* cnt = (float*)(ws + 8192);
    unsigned* ctrl1 = (unsigned*)(ws + 8208);
    unsigned* cntp = (unsigned*)(ws + 147456);
    unsigned* cntblk = (unsigned*)(ws + 147456);          // reuse cntp
    unsigned short* hist1p = (unsigned short*)(ws + 163840);
    unsigned* sbits = (unsigned*)(ws + 163840);           // reuse hist1p
    unsigned* sidx = (unsigned*)(ws + 425984);            // reuse hist1p
    unsigned short* mask16 = (unsigned short*)(ws + 688128);
    unsigned* wbits = (unsigned*)(ws + 1212416);

    k_prep<<<B_ * 256, 256, 0, stream>>>(y, proba, mask16, cntp, hist1p, wbits, cs2);
    k_class_sum<<<1029, 256, 0, stream>>>(emb, mask16, cs2, hist1p, cntp, ctrl1, cnt);
    k_collect<<<B_ * 256, 256, 0, stream>>>(wbits, ctrl1, cntblk, sbits, sidx);
    k_select<<<B_, 256, 0, stream>>>(ctrl1, cntblk, sbits, sidx, emb, y, avg, cs2, cnt, out);
}

// Round 15
// 99.507 us; speedup vs baseline: 1.0473x; 1.0473x over previous
//
#include <hip/hip_runtime.h>

#define B_ 4
#define C_ 4
#define V_ 262144
#define F_ 64
#define K_ 100
#define THETA 0.9f
#define TAU_ 0.1f

typedef unsigned long long ull;

// ---------------- workspace layout (bytes) ----------------
// cs2    : 0       .. 8192     (8 replicas x C x F f32; only c=1..3 used)
// cnt    : 8192    .. 8208     (C f32; only 1..3 used)
// ctrl1  : 8208    .. 8240     (B*2 u32: T1, n_above)
// cntp   : 147456  .. 163840   (1024*4 u32 count partials)  [prep->class_sum]
// cntblk : 147456  .. 151552   (B*256 u32 slot counts)      [collect->select, REUSES cntp]
// hist1p : 163840  .. 688128   (1024*256 u16 hist partials) [prep->class_sum]
// sbits  : 163840  .. 425984   (B*256*64 u32 slot bits)     [collect->select, REUSES hist1p]
// sidx   : 425984  .. 688128   (B*256*64 u32 slot idx)      [collect->select, REUSES hist1p]
// mask16 : 688128  .. 1212416  (B*V/4 u16 packed class masks; bits 1..3)
// wbits  : 1212416 .. 5406720  (B*V u32 product-weight float bits)
// Region reuse safe: hist1p/cntp fully consumed by k_class_sum before k_collect
// overwrites them (serial stream order).
// LESSON (r14): class_sum = 32KB LDS -> 4 blocks/CU -> 1024 streaming blocks
// fill the machine in EXACTLY one residency wave. The 5 scalar blocks MUST be
// dispatched at the TAIL (blocks 1024-1028); putting them first pushes 5
// streamers into a second round (+25us).

// Fused: init + y->mask16/count-partials + proba->wbits/hist1-partials.
__global__ __launch_bounds__(256) void k_prep(const int* __restrict__ y,
                                              const float* __restrict__ proba,
                                              unsigned short* __restrict__ mask16,
                                              unsigned* __restrict__ cntp,
                                              unsigned short* __restrict__ hist1p,
                                              unsigned* __restrict__ wbits,
                                              float* __restrict__ cs2) {
    __shared__ unsigned lh[256];
    __shared__ unsigned wc[4][2];
    int blk = blockIdx.x;
    int tid = threadIdx.x;
    int wave = tid >> 6, lane = tid & 63;
    int b = blk >> 8;
    int i4 = ((blk & 255) << 8) | tid;   // float4-group in [0, V/4)

    lh[tid] = 0u;
    if (blk < 8) cs2[(blk << 8) | tid] = 0.f;   // folded init (consumed later)
    __syncthreads();

    // ---- y (classes 1..3 only; class 0 dead in output) -> masks + counts ----
    const int4* y1 = (const int4*)(y + ((size_t)(b * C_ + 1)) * V_);
    const int4* y2 = (const int4*)(y + ((size_t)(b * C_ + 2)) * V_);
    const int4* y3 = (const int4*)(y + ((size_t)(b * C_ + 3)) * V_);
    int4 yb = y1[i4], yc = y2[i4], yd = y3[i4];

    unsigned n0 = ((unsigned)(yb.x > 0) << 1) | ((unsigned)(yc.x > 0) << 2) | ((unsigned)(yd.x > 0) << 3);
    unsigned n1 = ((unsigned)(yb.y > 0) << 1) | ((unsigned)(yc.y > 0) << 2) | ((unsigned)(yd.y > 0) << 3);
    unsigned n2 = ((unsigned)(yb.z > 0) << 1) | ((unsigned)(yc.z > 0) << 2) | ((unsigned)(yd.z > 0) << 3);
    unsigned n3 = ((unsigned)(yb.w > 0) << 1) | ((unsigned)(yc.w > 0) << 2) | ((unsigned)(yd.w > 0) << 3);
    mask16[(size_t)b * (V_ / 4) + i4] = (unsigned short)(n0 | (n1 << 4) | (n2 << 8) | (n3 << 12));

    unsigned p12 = ((unsigned)(yb.x > 0) + (yb.y > 0) + (yb.z > 0) + (yb.w > 0))
                 | (((unsigned)(yc.x > 0) + (yc.y > 0) + (yc.z > 0) + (yc.w > 0)) << 16);
    unsigned p3 = (unsigned)(yd.x > 0) + (yd.y > 0) + (yd.z > 0) + (yd.w > 0);
    #pragma unroll
    for (int o = 1; o < 64; o <<= 1) {
        p12 += __shfl_xor(p12, o, 64);
        p3 += __shfl_xor(p3, o, 64);
    }
    if (lane == 0) { wc[wave][0] = p12; wc[wave][1] = p3; }

    // ---- proba -> wbits + LDS hist1 ----
    const float* p0 = proba + (size_t)(b * C_) * V_;
    float4 qa = ((const float4*)p0)[i4];
    float4 qb = ((const float4*)(p0 + V_))[i4];
    float4 qc = ((const float4*)(p0 + 2 * V_))[i4];
    float4 qd = ((const float4*)(p0 + 3 * V_))[i4];
    uint4 wb;
    wb.x = __float_as_uint(((qa.x * qb.x) * qc.x) * qd.x);
    wb.y = __float_as_uint(((qa.y * qb.y) * qc.y) * qd.y);
    wb.z = __float_as_uint(((qa.z * qb.z) * qc.z) * qd.z);
    wb.w = __float_as_uint(((qa.w * qb.w) * qc.w) * qd.w);
    ((uint4*)wbits)[(size_t)b * (V_ / 4) + i4] = wb;
    atomicAdd(&lh[wb.x >> 24], 1u);
    atomicAdd(&lh[wb.y >> 24], 1u);
    atomicAdd(&lh[wb.z >> 24], 1u);
    atomicAdd(&lh[wb.w >> 24], 1u);
    __syncthreads();

    hist1p[(blk << 8) | tid] = (unsigned short)lh[tid];
    if (tid == 0) {
        unsigned q12 = wc[0][0] + wc[1][0] + wc[2][0] + wc[3][0];
        unsigned q3 = wc[0][1] + wc[1][1] + wc[2][1] + wc[3][1];
        unsigned* o4 = cntp + (blk << 2);
        o4[0] = 0u; o4[1] = q12 & 0xFFFFu;
        o4[2] = q12 >> 16; o4[3] = q3;
    }
}

// class_sum (c=1..3): blocks 0..1023 stream emb (exactly one residency wave);
// TAIL blocks 1024..1027 thresh0, 1028 cnt-reduce.
__global__ __launch_bounds__(256) void k_class_sum(const float* __restrict__ emb,
                                                   const unsigned short* __restrict__ mask16,
                                                   float* __restrict__ cs2,
                                                   const unsigned short* __restrict__ hist1p,
                                                   const unsigned* __restrict__ cntp,
                                                   unsigned* __restrict__ ctrl1,
                                                   float* __restrict__ cnt) {
    __shared__ unsigned short smask[16384];
    __shared__ unsigned bins[256];
    __shared__ float wsum[4][4];
    int blk = blockIdx.x;
    int tid = threadIdx.x;
    int wave = tid >> 6, lane = tid & 63;

    if (blk >= 1024) {
        if (blk < 1028) {
            int b = blk - 1024;
            unsigned s = 0;
            #pragma unroll 8
            for (int c = 0; c < 256; ++c)
                s += hist1p[(((b << 8) | c) << 8) | tid];
            bins[tid] = s;
            __syncthreads();
            if (wave == 0) {
                int binbase = 255 - 4 * lane;
                unsigned c0 = bins[binbase], c1 = bins[binbase - 1], c2 = bins[binbase - 2], c3 = bins[binbase - 3];
                unsigned cnt4 = c0 + c1 + c2 + c3;
                unsigned pref = cnt4;
                #pragma unroll
                for (int o = 1; o < 64; o <<= 1) {
                    unsigned u = __shfl_up(pref, o, 64);
                    if (lane >= o) pref += u;
                }
                unsigned above = pref - cnt4;
                unsigned t = above;
                int found = -1; unsigned nab = 0;
                if (t + c0 >= K_)                { found = binbase;     nab = t; }
                else if (t + c0 + c1 >= K_)      { found = binbase - 1; nab = t + c0; }
                else if (t + c0 + c1 + c2 >= K_) { found = binbase - 2; nab = t + c0 + c1; }
                else if (t + cnt4 >= K_)         { found = binbase - 3; nab = t + c0 + c1 + c2; }
                if (found >= 0 && above < K_) {
                    ctrl1[b * 2] = (unsigned)found;
                    ctrl1[b * 2 + 1] = nab;
                }
            }
        } else if (wave == 0) {
            unsigned s1 = 0, s2 = 0, s3 = 0;
            #pragma unroll
            for (int r = 0; r < 16; ++r) {
                uint4 p = ((const uint4*)cntp)[(r << 6) | lane];
                s1 += p.y; s2 += p.z; s3 += p.w;
            }
            #pragma unroll
            for (int o = 1; o < 64; o <<= 1) {
                s1 += __shfl_xor(s1, o, 64);
                s2 += __shfl_xor(s2, o, 64);
                s3 += __shfl_xor(s3, o, 64);
            }
            if (lane == 0) {
                cnt[0] = 0.f; cnt[1] = (float)s1;
                cnt[2] = (float)s2; cnt[3] = (float)s3;
            }
        }
        return;
    }

    int s = blk & 3;
    int f = (blk >> 2) & 63;
    int b = blk >> 8;

    {
        const uint4* msrc = (const uint4*)(mask16 + (size_t)b * (V_ / 4) + (s << 14));
        uint4* mdst = (uint4*)smask;
        #pragma unroll
        for (int i = 0; i < 8; ++i) mdst[(i << 8) | tid] = msrc[(i << 8) | tid];
    }
    __syncthreads();

    const float4* ep = (const float4*)emb + ((size_t)((b << 6) | f)) * (V_ / 4) + ((size_t)s << 14);

    float a1 = 0.f, a2 = 0.f, a3 = 0.f;
    for (int o = 0; o < 8; ++o) {
        float4 e[8];
        unsigned mm[8];
        #pragma unroll
        for (int i = 0; i < 8; ++i) e[i] = ep[(((o << 3) | i) << 8) | tid];
        #pragma unroll
        for (int i = 0; i < 8; ++i) mm[i] = smask[(((o << 3) | i) << 8) | tid];
        #pragma unroll
        for (int i = 0; i < 8; ++i) {
            unsigned m = mm[i];
            float4 ev = e[i];
            a1 += ((m >>  1) & 1u ? ev.x : 0.f) + ((m >>  5) & 1u ? ev.y : 0.f)
                + ((m >>  9) & 1u ? ev.z : 0.f) + ((m >> 13) & 1u ? ev.w : 0.f);
            a2 += ((m >>  2) & 1u ? ev.x : 0.f) + ((m >>  6) & 1u ? ev.y : 0.f)
                + ((m >> 10) & 1u ? ev.z : 0.f) + ((m >> 14) & 1u ? ev.w : 0.f);
            a3 += ((m >>  3) & 1u ? ev.x : 0.f) + ((m >>  7) & 1u ? ev.y : 0.f)
                + ((m >> 11) & 1u ? ev.z : 0.f) + ((m >> 15) & 1u ? ev.w : 0.f);
        }
    }
    #pragma unroll
    for (int o = 1; o < 64; o <<= 1) {
        a1 += __shfl_xor(a1, o, 64);
        a2 += __shfl_xor(a2, o, 64);
        a3 += __shfl_xor(a3, o, 64);
    }
    if (lane == 0) { wsum[wave][0] = a1; wsum[wave][1] = a2; wsum[wave][2] = a3; }
    __syncthreads();
    if (tid < 3) {
        float v = wsum[0][tid] + wsum[1][tid] + wsum[2][tid] + wsum[3][tid];
        atomicAdd(&cs2[((blk & 7) << 8) | ((tid + 1) << 6) | f], v);
    }
}

// T1-level collect into per-block fixed slots (NO global atomics).
__global__ __launch_bounds__(256) void k_collect(const unsigned* __restrict__ wbits,
                                                 const unsigned* __restrict__ ctrl1,
                                                 unsigned* __restrict__ cntblk,
                                                 unsigned* __restrict__ sbits,
                                                 unsigned* __restrict__ sidx) {
    __shared__ unsigned lcnt;
    int blk = blockIdx.x;
    int b = blk >> 8;
    int cb = blk & 255;
    int tid = threadIdx.x;
    if (tid == 0) lcnt = 0u;
    __syncthreads();
    unsigned T1 = ctrl1[b * 2];
    int base = cb << 10;
    int sb = ((b << 8) | cb) << 6;
    #pragma unroll
    for (int it = 0; it < 4; ++it) {
        int v = base + tid + (it << 8);
        unsigned bits = wbits[(size_t)b * V_ + v];
        if ((bits >> 24) >= T1) {
            unsigned pos = atomicAdd(&lcnt, 1u);   // LDS atomic, shallow
            if (pos < 64u) { sbits[sb | pos] = bits; sidx[sb | pos] = (unsigned)v; }
        }
    }
    __syncthreads();
    if (tid == 0) cntblk[(b << 8) | cb] = (lcnt < 64u) ? lcnt : 64u;
}

// bitonic compare-exchange (descending, 512 virtual lanes, 8 keys/lane)
#define XSTEP(kk_, k_, j_) { \
    _Pragma("unroll") \
    for (int r = 0; r < 8; ++r) { \
        ull o = __shfl_xor(kk_[r], (j_) >> 3, 64); \
        int p = (lane << 3) | r; \
        bool keepmax = (((p & (k_)) == 0) == ((p & (j_)) == 0)); \
        kk_[r] = (keepmax == (kk_[r] > o)) ? kk_[r] : o; \
    } }
#define LSTEP(kk_, k_, j_) { \
    _Pragma("unroll") \
    for (int r = 0; r < 8; ++r) { \
        if (!(r & (j_))) { \
            int p = (lane << 3) | r; \
            bool up = ((p & (k_)) == 0); \
            ull a = kk_[r], c = kk_[r | (j_)]; \
            ull mx = a > c ? a : c, mn = a > c ? c : a; \
            kk_[r] = up ? mx : mn; \
            kk_[r | (j_)] = up ? mn : mx; \
        } \
    } }

// Fused refine+select+final: LDS hist2 -> P16 -> filter -> bitonic -> epilogue.
__global__ __launch_bounds__(256) void k_select(const unsigned* __restrict__ ctrl1,
                                                const unsigned* __restrict__ cntblk,
                                                const unsigned* __restrict__ sbits,
                                                const unsigned* __restrict__ sidx,
                                                const float* __restrict__ emb,
                                                const int* __restrict__ y,
                                                const float* __restrict__ avg,
                                                const float* __restrict__ cs2,
                                                const float* __restrict__ cnt,
                                                float* __restrict__ out) {
    __shared__ unsigned hist[256];
    __shared__ ull keys[512];
    __shared__ unsigned topv[112];
    __shared__ unsigned P16s, fcnt;
    int b = blockIdx.x;
    int tid = threadIdx.x;
    int wave = tid >> 6, lane = tid & 63;
    unsigned T1 = ctrl1[b * 2];
    unsigned nab = ctrl1[b * 2 + 1];

    hist[tid] = 0u;
    keys[tid] = 0ull;
    keys[tid + 256] = 0ull;
    if (tid == 0) fcnt = 0u;
    __syncthreads();

    int c = (int)cntblk[(b << 8) | tid];   // thread t owns source chunk t
    int sb = ((b << 8) | tid) << 6;
    for (int i = 0; i < c; ++i) {
        unsigned bits = sbits[sb | i];
        if ((bits >> 24) == T1) atomicAdd(&hist[(bits >> 16) & 0xFF], 1u);
    }
    __syncthreads();

    if (wave == 0) {   // descending scan -> T2 -> P16
        int binbase = 255 - 4 * lane;
        unsigned c0 = hist[binbase], c1 = hist[binbase - 1], c2 = hist[binbase - 2], c3 = hist[binbase - 3];
        unsigned cnt4 = c0 + c1 + c2 + c3;
        unsigned pref = cnt4;
        #pragma unroll
        for (int o = 1; o < 64; o <<= 1) {
            unsigned u = __shfl_up(pref, o, 64);
            if (lane >= o) pref += u;
        }
        unsigned above = nab + pref - cnt4;
        unsigned t = above;
        int found = -1;
        if (t + c0 >= K_)                { found = binbase;     }
        else if (t + c0 + c1 >= K_)      { found = binbase - 1; }
        else if (t + c0 + c1 + c2 >= K_) { found = binbase - 2; }
        else if (t + cnt4 >= K_)         { found = binbase - 3; }
        if (found >= 0 && above < K_) P16s = (T1 << 8) | (unsigned)found;
    }
    __syncthreads();

    unsigned P16 = P16s;
    for (int i = 0; i < c; ++i) {
        unsigned bits = sbits[sb | i];
        if ((bits >> 16) >= P16) {
            unsigned pos = atomicAdd(&fcnt, 1u);
            if (pos < 512u) keys[pos] = ((ull)bits << 32) | (unsigned)(~sidx[sb | i]);
        }
    }
    __syncthreads();

    if (wave == 0) {   // exact (bits desc, idx asc) == lax.top_k order
        ull kk[8];
        #pragma unroll
        for (int r = 0; r < 8; ++r) kk[r] = keys[(lane << 3) | r];
        LSTEP(kk, 2, 1)
        LSTEP(kk, 4, 2) LSTEP(kk, 4, 1)
        LSTEP(kk, 8, 4) LSTEP(kk, 8, 2) LSTEP(kk, 8, 1)
        XSTEP(kk, 16, 8) LSTEP(kk, 16, 4) LSTEP(kk, 16, 2) LSTEP(kk, 16, 1)
        XSTEP(kk, 32, 16) XSTEP(kk, 32, 8) LSTEP(kk, 32, 4) LSTEP(kk, 32, 2) LSTEP(kk, 32, 1)
        XSTEP(kk, 64, 32) XSTEP(kk, 64, 16) XSTEP(kk, 64, 8) LSTEP(kk, 64, 4) LSTEP(kk, 64, 2) LSTEP(kk, 64, 1)
        XSTEP(kk, 128, 64) XSTEP(kk, 128, 32) XSTEP(kk, 128, 16) XSTEP(kk, 128, 8) LSTEP(kk, 128, 4) LSTEP(kk, 128, 2) LSTEP(kk, 128, 1)
        XSTEP(kk, 256, 128) XSTEP(kk, 256, 64) XSTEP(kk, 256, 32) XSTEP(kk, 256, 16) XSTEP(kk, 256, 8) LSTEP(kk, 256, 4) LSTEP(kk, 256, 2) LSTEP(kk, 256, 1)
        XSTEP(kk, 512, 256) XSTEP(kk, 512, 128) XSTEP(kk, 512, 64) XSTEP(kk, 512, 32) XSTEP(kk, 512, 16) XSTEP(kk, 512, 8) LSTEP(kk, 512, 4) LSTEP(kk, 512, 2) LSTEP(kk, 512, 1)
        #pragma unroll
        for (int r = 0; r < 8; ++r) {
            int p = (lane << 3) | r;
            if (p < K_) topv[p] = ~(unsigned)(kk[r] & 0xFFFFFFFFull);
        }
    }
    __syncthreads();

    // ---- fused final: nar hoisted per block; wave w does k = 25w..25w+24 ----
    float nar[3];
    #pragma unroll
    for (int cc_ = 1; cc_ < 4; ++cc_) {
        float ccv = cnt[cc_];
        float csum = 0.f;
        #pragma unroll
        for (int rep = 0; rep < 8; ++rep) csum += cs2[(rep << 8) | (cc_ << 6) | lane];
        float mean = csum / fmaxf(ccv, 1.f);
        float av = avg[cc_ * F_ + lane];
        nar[cc_ - 1] = (ccv > 0.f) ? (av * (1.f - THETA) + mean * THETA) : av;
    }
    const float* erow = emb + ((size_t)((b << 6) | lane)) * V_;
    const int* y0p = y + ((size_t)(b * C_ + 0)) * V_;
    const int* y1p = y + ((size_t)(b * C_ + 1)) * V_;
    const int* y2p = y + ((size_t)(b * C_ + 2)) * V_;
    const int* y3p = y + ((size_t)(b * C_ + 3)) * V_;

    for (int j = 0; j < 5; ++j) {
        float ee[5];
        int yv0[5], yv1[5], yv2[5], yv3[5];
        #pragma unroll
        for (int i = 0; i < 5; ++i) {
            unsigned v = topv[wave * 25 + j * 5 + i];
            ee[i] = erow[v];
            yv0[i] = y0p[v]; yv1[i] = y1p[v]; yv2[i] = y2p[v]; yv3[i] = y3p[v];
        }
        #pragma unroll
        for (int i = 0; i < 5; ++i) {
            int k = wave * 25 + j * 5 + i;
            int cm = (yv0[i] > 0) ? 0 : ((yv1[i] > 0) ? 1 : ((yv2[i] > 0) ? 2 : ((yv3[i] > 0) ? 3 : 0)));
            float sel = (cm == 0) ? 1.f : 0.f;
            float t = ee[i] / TAU_;
            float ssum = 0.f;
            #pragma unroll
            for (int cc_ = 0; cc_ < 3; ++cc_) ssum += expf(t * nar[cc_]);
            float term = -logf(ssum);
            #pragma unroll
            for (int o = 32; o > 0; o >>= 1) term += __shfl_down(term, o, 64);
            if (lane == 0) out[b * K_ + k] = term * sel;
        }
    }
}

extern "C" void kernel_launch(void* const* d_in, const int* in_sizes, int n_in,
                              void* d_out, int out_size, void* d_ws, size_t ws_size,
                              hipStream_t stream) {
    const float* proba = (const float*)d_in[0];
    const int* y = (const int*)d_in[1];
    const float* emb = (const float*)d_in[2];
    const float* avg = (const float*)d_in[3];
    float* out = (float*)d_out;

    char* ws = (char*)d_ws;
    float* cs2 = (float*)(ws + 0);
    float* cnt = (float*)(ws + 8192);
    unsigned* ctrl1 = (unsigned*)(ws + 8208);
    unsigned* cntp = (unsigned*)(ws + 147456);
    unsigned* cntblk = (unsigned*)(ws + 147456);          // reuse cntp
    unsigned short* hist1p = (unsigned short*)(ws + 163840);
    unsigned* sbits = (unsigned*)(ws + 163840);           // reuse hist1p
    unsigned* sidx = (unsigned*)(ws + 425984);            // reuse hist1p
    unsigned short* mask16 = (unsigned short*)(ws + 688128);
    unsigned* wbits = (unsigned*)(ws + 1212416);

    k_prep<<<B_ * 256, 256, 0, stream>>>(y, proba, mask16, cntp, hist1p, wbits, cs2);
    k_class_sum<<<1029, 256, 0, stream>>>(emb, mask16, cs2, hist1p, cntp, ctrl1, cnt);
    k_collect<<<B_ * 256, 256, 0, stream>>>(wbits, ctrl1, cntblk, sbits, sidx);
    k_select<<<B_, 256, 0, stream>>>(ctrl1, cntblk, sbits, sidx, emb, y, avg, cs2, cnt, out);
}

// Round 16
// 77.677 us; speedup vs baseline: 1.3416x; 1.2810x over previous
//
#include <hip/hip_runtime.h>

#define B_ 4
#define C_ 4
#define V_ 262144
#define F_ 64
#define K_ 100
#define THETA 0.9f
#define TAU_ 0.1f

typedef unsigned long long ull;

// ---------------- workspace layout (bytes) ----------------
// cs2    : 0       .. 8192     (8 replicas x C x F f32; only c=1..3 used)
// cnt    : 8192    .. 8208     (C f32; only 1..3 used)
// ctrl1  : 8208    .. 8240     (B*2 u32: T1, n_above)
// idxout : 8320    .. 9920     (B*K u32)
// cntp   : 147456  .. 163840   (1024*4 u32 count partials)  [prep->class_sum]
// cntblk : 147456  .. 151552   (B*256 u32 slot counts)      [collect->select, REUSES cntp]
// hist1p : 163840  .. 688128   (1024*256 u16 hist partials) [prep->class_sum]
// sbits  : 163840  .. 425984   (B*256*64 u32 slot bits)     [collect->select, REUSES hist1p]
// sidx   : 425984  .. 688128   (B*256*64 u32 slot idx)      [collect->select, REUSES hist1p]
// mask16 : 688128  .. 1212416  (B*V/4 u16 packed class masks; bits 1..3)
// wbits  : 1212416 .. 5406720  (B*V u32 product-weight float bits)
// LESSONS baked in: (r9) grid.sync ~115us/sync; (r10) tiny memsetAsync ~155us
// in graph; (r6) same-address atomic chains ~125cy each; (r14) scalar tail
// blocks must dispatch AFTER the streaming blocks; (r15) latency-bound gather
// epilogue needs a 400-block grid, do NOT fuse into the 4-block select.

// Fused: init + y->mask16/count-partials + proba->wbits/hist1-partials.
__global__ __launch_bounds__(256) void k_prep(const int* __restrict__ y,
                                              const float* __restrict__ proba,
                                              unsigned short* __restrict__ mask16,
                                              unsigned* __restrict__ cntp,
                                              unsigned short* __restrict__ hist1p,
                                              unsigned* __restrict__ wbits,
                                              float* __restrict__ cs2) {
    __shared__ unsigned lh[256];
    __shared__ unsigned wc[4][2];
    int blk = blockIdx.x;
    int tid = threadIdx.x;
    int wave = tid >> 6, lane = tid & 63;
    int b = blk >> 8;
    int i4 = ((blk & 255) << 8) | tid;   // float4-group in [0, V/4)

    lh[tid] = 0u;
    if (blk < 8) cs2[(blk << 8) | tid] = 0.f;   // folded init (consumed later)
    __syncthreads();

    // ---- y (classes 1..3 only; class 0 dead in output) -> masks + counts ----
    const int4* y1 = (const int4*)(y + ((size_t)(b * C_ + 1)) * V_);
    const int4* y2 = (const int4*)(y + ((size_t)(b * C_ + 2)) * V_);
    const int4* y3 = (const int4*)(y + ((size_t)(b * C_ + 3)) * V_);
    int4 yb = y1[i4], yc = y2[i4], yd = y3[i4];

    unsigned n0 = ((unsigned)(yb.x > 0) << 1) | ((unsigned)(yc.x > 0) << 2) | ((unsigned)(yd.x > 0) << 3);
    unsigned n1 = ((unsigned)(yb.y > 0) << 1) | ((unsigned)(yc.y > 0) << 2) | ((unsigned)(yd.y > 0) << 3);
    unsigned n2 = ((unsigned)(yb.z > 0) << 1) | ((unsigned)(yc.z > 0) << 2) | ((unsigned)(yd.z > 0) << 3);
    unsigned n3 = ((unsigned)(yb.w > 0) << 1) | ((unsigned)(yc.w > 0) << 2) | ((unsigned)(yd.w > 0) << 3);
    mask16[(size_t)b * (V_ / 4) + i4] = (unsigned short)(n0 | (n1 << 4) | (n2 << 8) | (n3 << 12));

    unsigned p12 = ((unsigned)(yb.x > 0) + (yb.y > 0) + (yb.z > 0) + (yb.w > 0))
                 | (((unsigned)(yc.x > 0) + (yc.y > 0) + (yc.z > 0) + (yc.w > 0)) << 16);
    unsigned p3 = (unsigned)(yd.x > 0) + (yd.y > 0) + (yd.z > 0) + (yd.w > 0);
    #pragma unroll
    for (int o = 1; o < 64; o <<= 1) {
        p12 += __shfl_xor(p12, o, 64);
        p3 += __shfl_xor(p3, o, 64);
    }
    if (lane == 0) { wc[wave][0] = p12; wc[wave][1] = p3; }

    // ---- proba -> wbits + LDS hist1 ----
    const float* p0 = proba + (size_t)(b * C_) * V_;
    float4 qa = ((const float4*)p0)[i4];
    float4 qb = ((const float4*)(p0 + V_))[i4];
    float4 qc = ((const float4*)(p0 + 2 * V_))[i4];
    float4 qd = ((const float4*)(p0 + 3 * V_))[i4];
    uint4 wb;
    wb.x = __float_as_uint(((qa.x * qb.x) * qc.x) * qd.x);
    wb.y = __float_as_uint(((qa.y * qb.y) * qc.y) * qd.y);
    wb.z = __float_as_uint(((qa.z * qb.z) * qc.z) * qd.z);
    wb.w = __float_as_uint(((qa.w * qb.w) * qc.w) * qd.w);
    ((uint4*)wbits)[(size_t)b * (V_ / 4) + i4] = wb;
    atomicAdd(&lh[wb.x >> 24], 1u);
    atomicAdd(&lh[wb.y >> 24], 1u);
    atomicAdd(&lh[wb.z >> 24], 1u);
    atomicAdd(&lh[wb.w >> 24], 1u);
    __syncthreads();

    hist1p[(blk << 8) | tid] = (unsigned short)lh[tid];
    if (tid == 0) {
        unsigned q12 = wc[0][0] + wc[1][0] + wc[2][0] + wc[3][0];
        unsigned q3 = wc[0][1] + wc[1][1] + wc[2][1] + wc[3][1];
        unsigned* o4 = cntp + (blk << 2);
        o4[0] = 0u; o4[1] = q12 & 0xFFFFu;
        o4[2] = q12 >> 16; o4[3] = q3;
    }
}

// class_sum (c=1..3): blocks 0..2047 stream emb with 16KB LDS masks
// (8 blocks/CU, 32 waves/CU = full occupancy, ONE residency wave);
// TAIL blocks 2048..2051 thresh0, 2052 cnt-reduce.
__global__ __launch_bounds__(256) void k_class_sum(const float* __restrict__ emb,
                                                   const unsigned short* __restrict__ mask16,
                                                   float* __restrict__ cs2,
                                                   const unsigned short* __restrict__ hist1p,
                                                   const unsigned* __restrict__ cntp,
                                                   unsigned* __restrict__ ctrl1,
                                                   float* __restrict__ cnt) {
    __shared__ unsigned short smask[8192];   // 16 KB: masks for 32768 v
    __shared__ unsigned bins[256];
    __shared__ float wsum[4][4];
    int blk = blockIdx.x;
    int tid = threadIdx.x;
    int wave = tid >> 6, lane = tid & 63;

    if (blk >= 2048) {
        if (blk < 2052) {
            int b = blk - 2048;
            unsigned s = 0;
            #pragma unroll 8
            for (int c = 0; c < 256; ++c)
                s += hist1p[(((b << 8) | c) << 8) | tid];
            bins[tid] = s;
            __syncthreads();
            if (wave == 0) {
                int binbase = 255 - 4 * lane;
                unsigned c0 = bins[binbase], c1 = bins[binbase - 1], c2 = bins[binbase - 2], c3 = bins[binbase - 3];
                unsigned cnt4 = c0 + c1 + c2 + c3;
                unsigned pref = cnt4;
                #pragma unroll
                for (int o = 1; o < 64; o <<= 1) {
                    unsigned u = __shfl_up(pref, o, 64);
                    if (lane >= o) pref += u;
                }
                unsigned above = pref - cnt4;
                unsigned t = above;
                int found = -1; unsigned nab = 0;
                if (t + c0 >= K_)                { found = binbase;     nab = t; }
                else if (t + c0 + c1 >= K_)      { found = binbase - 1; nab = t + c0; }
                else if (t + c0 + c1 + c2 >= K_) { found = binbase - 2; nab = t + c0 + c1; }
                else if (t + cnt4 >= K_)         { found = binbase - 3; nab = t + c0 + c1 + c2; }
                if (found >= 0 && above < K_) {
                    ctrl1[b * 2] = (unsigned)found;
                    ctrl1[b * 2 + 1] = nab;
                }
            }
        } else if (wave == 0) {
            unsigned s1 = 0, s2 = 0, s3 = 0;
            #pragma unroll
            for (int r = 0; r < 16; ++r) {
                uint4 p = ((const uint4*)cntp)[(r << 6) | lane];
                s1 += p.y; s2 += p.z; s3 += p.w;
            }
            #pragma unroll
            for (int o = 1; o < 64; o <<= 1) {
                s1 += __shfl_xor(s1, o, 64);
                s2 += __shfl_xor(s2, o, 64);
                s3 += __shfl_xor(s3, o, 64);
            }
            if (lane == 0) {
                cnt[0] = 0.f; cnt[1] = (float)s1;
                cnt[2] = (float)s2; cnt[3] = (float)s3;
            }
        }
        return;
    }

    // blk = b(2b) | f(6b) | s(3b): segment s of 32768 v in row (b,f)
    int s = blk & 7;
    int f = (blk >> 3) & 63;
    int b = blk >> 9;

    {
        const uint4* msrc = (const uint4*)(mask16 + (size_t)b * (V_ / 4) + (s << 13));
        uint4* mdst = (uint4*)smask;
        #pragma unroll
        for (int i = 0; i < 4; ++i) mdst[(i << 8) | tid] = msrc[(i << 8) | tid];
    }
    __syncthreads();

    const float4* ep = (const float4*)emb + ((size_t)((b << 6) | f)) * (V_ / 4) + ((size_t)s << 13);

    float a1 = 0.f, a2 = 0.f, a3 = 0.f;
    for (int o = 0; o < 4; ++o) {
        float4 e[8];
        unsigned mm[8];
        #pragma unroll
        for (int i = 0; i < 8; ++i) e[i] = ep[(((o << 3) | i) << 8) | tid];
        #pragma unroll
        for (int i = 0; i < 8; ++i) mm[i] = smask[(((o << 3) | i) << 8) | tid];
        #pragma unroll
        for (int i = 0; i < 8; ++i) {
            unsigned m = mm[i];
            float4 ev = e[i];
            a1 += ((m >>  1) & 1u ? ev.x : 0.f) + ((m >>  5) & 1u ? ev.y : 0.f)
                + ((m >>  9) & 1u ? ev.z : 0.f) + ((m >> 13) & 1u ? ev.w : 0.f);
            a2 += ((m >>  2) & 1u ? ev.x : 0.f) + ((m >>  6) & 1u ? ev.y : 0.f)
                + ((m >> 10) & 1u ? ev.z : 0.f) + ((m >> 14) & 1u ? ev.w : 0.f);
            a3 += ((m >>  3) & 1u ? ev.x : 0.f) + ((m >>  7) & 1u ? ev.y : 0.f)
                + ((m >> 11) & 1u ? ev.z : 0.f) + ((m >> 15) & 1u ? ev.w : 0.f);
        }
    }
    #pragma unroll
    for (int o = 1; o < 64; o <<= 1) {
        a1 += __shfl_xor(a1, o, 64);
        a2 += __shfl_xor(a2, o, 64);
        a3 += __shfl_xor(a3, o, 64);
    }
    if (lane == 0) { wsum[wave][0] = a1; wsum[wave][1] = a2; wsum[wave][2] = a3; }
    __syncthreads();
    if (tid < 3) {
        float v = wsum[0][tid] + wsum[1][tid] + wsum[2][tid] + wsum[3][tid];
        atomicAdd(&cs2[((blk & 7) << 8) | ((tid + 1) << 6) | f], v);   // 8-way spread
    }
}

// T1-level collect into per-block fixed slots (NO global atomics).
__global__ __launch_bounds__(256) void k_collect(const unsigned* __restrict__ wbits,
                                                 const unsigned* __restrict__ ctrl1,
                                                 unsigned* __restrict__ cntblk,
                                                 unsigned* __restrict__ sbits,
                                                 unsigned* __restrict__ sidx) {
    __shared__ unsigned lcnt;
    int blk = blockIdx.x;
    int b = blk >> 8;
    int cb = blk & 255;
    int tid = threadIdx.x;
    if (tid == 0) lcnt = 0u;
    __syncthreads();
    unsigned T1 = ctrl1[b * 2];
    int base = cb << 10;
    int sb = ((b << 8) | cb) << 6;
    #pragma unroll
    for (int it = 0; it < 4; ++it) {
        int v = base + tid + (it << 8);
        unsigned bits = wbits[(size_t)b * V_ + v];
        if ((bits >> 24) >= T1) {
            unsigned pos = atomicAdd(&lcnt, 1u);   // LDS atomic, shallow
            if (pos < 64u) { sbits[sb | pos] = bits; sidx[sb | pos] = (unsigned)v; }
        }
    }
    __syncthreads();
    if (tid == 0) cntblk[(b << 8) | cb] = (lcnt < 64u) ? lcnt : 64u;
}

// bitonic compare-exchange (descending, 512 virtual lanes, 8 keys/lane)
#define XSTEP(kk_, k_, j_) { \
    _Pragma("unroll") \
    for (int r = 0; r < 8; ++r) { \
        ull o = __shfl_xor(kk_[r], (j_) >> 3, 64); \
        int p = (lane << 3) | r; \
        bool keepmax = (((p & (k_)) == 0) == ((p & (j_)) == 0)); \
        kk_[r] = (keepmax == (kk_[r] > o)) ? kk_[r] : o; \
    } }
#define LSTEP(kk_, k_, j_) { \
    _Pragma("unroll") \
    for (int r = 0; r < 8; ++r) { \
        if (!(r & (j_))) { \
            int p = (lane << 3) | r; \
            bool up = ((p & (k_)) == 0); \
            ull a = kk_[r], c = kk_[r | (j_)]; \
            ull mx = a > c ? a : c, mn = a > c ? c : a; \
            kk_[r] = up ? mx : mn; \
            kk_[r | (j_)] = up ? mn : mx; \
        } \
    } }

// Fused refine+select: LDS hist2 -> P16 -> filter -> 512-wide bitonic.
__global__ __launch_bounds__(256) void k_select(const unsigned* __restrict__ ctrl1,
                                                const unsigned* __restrict__ cntblk,
                                                const unsigned* __restrict__ sbits,
                                                const unsigned* __restrict__ sidx,
                                                unsigned* __restrict__ idxout) {
    __shared__ unsigned hist[256];
    __shared__ ull keys[512];
    __shared__ unsigned P16s, fcnt;
    int b = blockIdx.x;
    int tid = threadIdx.x;
    int wave = tid >> 6, lane = tid & 63;
    unsigned T1 = ctrl1[b * 2];
    unsigned nab = ctrl1[b * 2 + 1];

    hist[tid] = 0u;
    keys[tid] = 0ull;
    keys[tid + 256] = 0ull;
    if (tid == 0) fcnt = 0u;
    __syncthreads();

    int c = (int)cntblk[(b << 8) | tid];   // thread t owns source chunk t
    int sb = ((b << 8) | tid) << 6;
    for (int i = 0; i < c; ++i) {
        unsigned bits = sbits[sb | i];
        if ((bits >> 24) == T1) atomicAdd(&hist[(bits >> 16) & 0xFF], 1u);
    }
    __syncthreads();

    if (wave == 0) {   // descending scan -> T2 -> P16
        int binbase = 255 - 4 * lane;
        unsigned c0 = hist[binbase], c1 = hist[binbase - 1], c2 = hist[binbase - 2], c3 = hist[binbase - 3];
        unsigned cnt4 = c0 + c1 + c2 + c3;
        unsigned pref = cnt4;
        #pragma unroll
        for (int o = 1; o < 64; o <<= 1) {
            unsigned u = __shfl_up(pref, o, 64);
            if (lane >= o) pref += u;
        }
        unsigned above = nab + pref - cnt4;
        unsigned t = above;
        int found = -1;
        if (t + c0 >= K_)                { found = binbase;     }
        else if (t + c0 + c1 >= K_)      { found = binbase - 1; }
        else if (t + c0 + c1 + c2 >= K_) { found = binbase - 2; }
        else if (t + cnt4 >= K_)         { found = binbase - 3; }
        if (found >= 0 && above < K_) P16s = (T1 << 8) | (unsigned)found;
    }
    __syncthreads();

    unsigned P16 = P16s;
    for (int i = 0; i < c; ++i) {
        unsigned bits = sbits[sb | i];
        if ((bits >> 16) >= P16) {
            unsigned pos = atomicAdd(&fcnt, 1u);
            if (pos < 512u) keys[pos] = ((ull)bits << 32) | (unsigned)(~sidx[sb | i]);
        }
    }
    __syncthreads();

    if (wave == 0) {   // exact (bits desc, idx asc) == lax.top_k order
        ull kk[8];
        #pragma unroll
        for (int r = 0; r < 8; ++r) kk[r] = keys[(lane << 3) | r];
        LSTEP(kk, 2, 1)
        LSTEP(kk, 4, 2) LSTEP(kk, 4, 1)
        LSTEP(kk, 8, 4) LSTEP(kk, 8, 2) LSTEP(kk, 8, 1)
        XSTEP(kk, 16, 8) LSTEP(kk, 16, 4) LSTEP(kk, 16, 2) LSTEP(kk, 16, 1)
        XSTEP(kk, 32, 16) XSTEP(kk, 32, 8) LSTEP(kk, 32, 4) LSTEP(kk, 32, 2) LSTEP(kk, 32, 1)
        XSTEP(kk, 64, 32) XSTEP(kk, 64, 16) XSTEP(kk, 64, 8) LSTEP(kk, 64, 4) LSTEP(kk, 64, 2) LSTEP(kk, 64, 1)
        XSTEP(kk, 128, 64) XSTEP(kk, 128, 32) XSTEP(kk, 128, 16) XSTEP(kk, 128, 8) LSTEP(kk, 128, 4) LSTEP(kk, 128, 2) LSTEP(kk, 128, 1)
        XSTEP(kk, 256, 128) XSTEP(kk, 256, 64) XSTEP(kk, 256, 32) XSTEP(kk, 256, 16) XSTEP(kk, 256, 8) LSTEP(kk, 256, 4) LSTEP(kk, 256, 2) LSTEP(kk, 256, 1)
        XSTEP(kk, 512, 256) XSTEP(kk, 512, 128) XSTEP(kk, 512, 64) XSTEP(kk, 512, 32) XSTEP(kk, 512, 16) XSTEP(kk, 512, 8) LSTEP(kk, 512, 4) LSTEP(kk, 512, 2) LSTEP(kk, 512, 1)
        #pragma unroll
        for (int r = 0; r < 8; ++r) {
            int p = (lane << 3) | r;
            if (p < K_) idxout[b * K_ + p] = ~(unsigned)(kk[r] & 0xFFFFFFFFull);
        }
    }
}

// final: one wave (64 lanes = F) per (b,k) — 400 blocks for gather latency
// hiding (r15 lesson: do NOT fuse into the 4-block select).
__global__ __launch_bounds__(64) void k_final(const float* __restrict__ emb,
                                              const int* __restrict__ y,
                                              const float* __restrict__ avg,
                                              const float* __restrict__ cs2,
                                              const float* __restrict__ cnt,
                                              const unsigned* __restrict__ idxout,
                                              float* __restrict__ out) {
    int blk = blockIdx.x;
    int b = blk / K_;
    int k = blk % K_;
    int lane = threadIdx.x;
    unsigned v = idxout[b * K_ + k];

    float e = emb[((size_t)(b * F_ + lane)) * V_ + v];

    int y0v = y[((size_t)(b * C_ + 0)) * V_ + v];
    int y1v = y[((size_t)(b * C_ + 1)) * V_ + v];
    int y2v = y[((size_t)(b * C_ + 2)) * V_ + v];
    int y3v = y[((size_t)(b * C_ + 3)) * V_ + v];
    int cm = (y0v > 0) ? 0 : ((y1v > 0) ? 1 : ((y2v > 0) ? 2 : ((y3v > 0) ? 3 : 0)));
    float sel = (cm == 0) ? 1.f : 0.f;

    float t = e / TAU_;
    float ssum = 0.f;
    #pragma unroll
    for (int c = 1; c < 4; ++c) {
        float cc = cnt[c];
        float csum = 0.f;
        #pragma unroll
        for (int rep = 0; rep < 8; ++rep) csum += cs2[(rep << 8) | (c << 6) | lane];
        float mean = csum / fmaxf(cc, 1.f);
        float av = avg[c * F_ + lane];
        float nar = (cc > 0.f) ? (av * (1.f - THETA) + mean * THETA) : av;
        ssum += expf(t * nar);
    }
    float term = -logf(ssum);
    #pragma unroll
    for (int o = 32; o > 0; o >>= 1) term += __shfl_down(term, o, 64);
    if (lane == 0) out[b * K_ + k] = term * sel;
}

extern "C" void kernel_launch(void* const* d_in, const int* in_sizes, int n_in,
                              void* d_out, int out_size, void* d_ws, size_t ws_size,
                              hipStream_t stream) {
    const float* proba = (const float*)d_in[0];
    const int* y = (const int*)d_in[1];
    const float* emb = (const float*)d_in[2];
    const float* avg = (const float*)d_in[3];
    float* out = (float*)d_out;

    char* ws = (char*)d_ws;
    float* cs2 = (float*)(ws + 0);
    float* cnt = (float*)(ws + 8192);
    unsigned* ctrl1 = (unsigned*)(ws + 8208);
    unsigned* idxout = (unsigned*)(ws + 8320);
    unsigned* cntp = (unsigned*)(ws + 147456);
    unsigned* cntblk = (unsigned*)(ws + 147456);          // reuse cntp
    unsigned short* hist1p = (unsigned short*)(ws + 163840);
    unsigned* sbits = (unsigned*)(ws + 163840);           // reuse hist1p
    unsigned* sidx = (unsigned*)(ws + 425984);            // reuse hist1p
    unsigned short* mask16 = (unsigned short*)(ws + 688128);
    unsigned* wbits = (unsigned*)(ws + 1212416);

    k_prep<<<B_ * 256, 256, 0, stream>>>(y, proba, mask16, cntp, hist1p, wbits, cs2);
    k_class_sum<<<2053, 256, 0, stream>>>(emb, mask16, cs2, hist1p, cntp, ctrl1, cnt);
    k_collect<<<B_ * 256, 256, 0, stream>>>(wbits, ctrl1, cntblk, sbits, sidx);
    k_select<<<B_, 256, 0, stream>>>(ctrl1, cntblk, sbits, sidx, idxout);
    k_final<<<B_ * K_, 64, 0, stream>>>(emb, y, avg, cs2, cnt, idxout, out);
}